// Round 8
// baseline (1185.202 us; speedup 1.0000x reference)
//
#include <hip/hip_runtime.h>

// Problem constants
#define NC   5
#define NU   6144
#define NV   6144
#define ND   64
#define NB   4096
#define CAP  128     // max nnz per row/col per class (mean 61.4, +8.5 sigma)
#define HALF (NC * NU)   // 30720 rows per side

typedef float vf4 __attribute__((ext_vector_type(4)));  // builtin-compatible

// spread bits of a byte to every 4th bit of a u32
__device__ __forceinline__ unsigned int spread4(unsigned int x) {
  x &= 0xFFu;
  x = (x | (x << 12)) & 0x000F000Fu;
  x = (x | (x << 6))  & 0x03030303u;
  x = (x | (x << 3))  & 0x11111111u;
  return x;
}

// ---------------------------------------------------------------------------
// One pass: dense adj [C,U,V] fp32 (exactly 0/1) -> CSR + CSC index lists.
// Tile = 256 u x 256 v per block (4x tail amortization vs 64x256).
// Each wave owns 64 rows, processed in 8 software-pipelined batches of
// 8 x 1KB nontemporal loads (next batch issued before current batch's
// pack/expand). Col-side masks accumulate in REGISTERS from each lane's
// own predicates (no LDS bit-transpose); one LDS merge + one atomic per
// nonempty column at the end.
// ---------------------------------------------------------------------------
__global__ __launch_bounds__(256) void k_adj2idx(
    const float* __restrict__ adj,
    int* __restrict__ cnt,                // [2*C*6144] (csr | csc)
    unsigned short* __restrict__ idx) {   // [2*C*6144][CAP]
  __shared__ unsigned int rowwords[256][9];  // per-wave-private 64-row bands
  __shared__ unsigned int colLDS[256][9];    // [col][wave*2+h] row-masks
  const int b = blockIdx.x;                  // c*576 + tu*24 + tv  (2880)
  const int c  = b / 576;
  const int rem = b - c * 576;
  const int tu = rem / 24;
  const int tv = rem - tu * 24;
  const int wave = threadIdx.x >> 6;
  const int lane = threadIdx.x & 63;
  const int R0 = wave * 64;                  // tile-row base for this wave

  unsigned int cacc[8];                      // col masks: cacc[k*2+h]
  #pragma unroll
  for (int k = 0; k < 8; ++k) cacc[k] = 0;

  const float* wbase = adj +
      ((size_t)(c * NU + tu * 256 + R0) * NV + tv * 256);

  vf4 av[8];
  #pragma unroll
  for (int rr = 0; rr < 8; ++rr)
    av[rr] = __builtin_nontemporal_load(
        (const vf4*)(wbase + (size_t)rr * NV) + lane);

  for (int batch = 0; batch < 8; ++batch) {
    // ---- prefetch next batch while we pack/expand this one ----
    vf4 nv[8];
    if (batch < 7) {
      const float* nb = wbase + (size_t)(batch + 1) * 8 * NV;
      #pragma unroll
      for (int rr = 0; rr < 8; ++rr)
        nv[rr] = __builtin_nontemporal_load(
            (const vf4*)(nb + (size_t)rr * NV) + lane);
    }

    // ---- ballot-pack 8 rows + accumulate col masks in registers ----
    #pragma unroll
    for (int rr = 0; rr < 8; ++rr) {
      const int r = batch * 8 + rr;          // 0..63 within wave band
      const unsigned long long b0 = __ballot(av[rr].x != 0.0f);
      const unsigned long long b1 = __ballot(av[rr].y != 0.0f);
      const unsigned long long b2 = __ballot(av[rr].z != 0.0f);
      const unsigned long long b3 = __ballot(av[rr].w != 0.0f);
      if (lane < 8) {                  // word w covers cols w*32..w*32+31
        const unsigned int e0 = spread4((unsigned int)(b0 >> (lane * 8)));
        const unsigned int e1 = spread4((unsigned int)(b1 >> (lane * 8)));
        const unsigned int e2 = spread4((unsigned int)(b2 >> (lane * 8)));
        const unsigned int e3 = spread4((unsigned int)(b3 >> (lane * 8)));
        rowwords[R0 + r][lane] = e0 | (e1 << 1) | (e2 << 2) | (e3 << 3);
      }
      // lane's own 4 columns (4*lane+k), bit r of lo/hi word
      const unsigned int bit = 1u << (r & 31);
      const int h = r >> 5;
      if (av[rr].x != 0.0f) cacc[0 + h] |= bit;
      if (av[rr].y != 0.0f) cacc[2 + h] |= bit;
      if (av[rr].z != 0.0f) cacc[4 + h] |= bit;
      if (av[rr].w != 0.0f) cacc[6 + h] |= bit;
    }
    __threadfence_block();   // order wave-local LDS write -> read (lgkmcnt)

    // ---- row-side expansion for these 8 rows (wave-local) ----
    {
      const int rloc = lane >> 3;      // row within batch (0..7)
      const int wloc = lane & 7;       // word (0..7)
      const unsigned int wbits = rowwords[R0 + batch * 8 + rloc][wloc];
      const int pc = __popc(wbits);
      int pre = pc;                    // inclusive prefix within 8-lane group
      #pragma unroll
      for (int d = 1; d < 8; d <<= 1) {
        const int y = __shfl_up(pre, d, 64);
        if (wloc >= d) pre += y;
      }
      const int total = __shfl(pre, rloc * 8 + 7, 64);
      const int excl  = pre - pc;
      const int R = c * 6144 + tu * 256 + R0 + batch * 8 + rloc;
      int base = 0;
      if (wloc == 0 && total > 0) base = atomicAdd(&cnt[R], total);
      base = __shfl(base, rloc * 8, 64);
      unsigned int m = wbits;
      int o = base + excl;
      unsigned short* orow = idx + (size_t)R * CAP;
      const int vbase = tv * 256 + wloc * 32;
      while (m) {
        const int bb = __ffs(m) - 1;
        if (o < CAP) orow[o] = (unsigned short)(vbase + bb);
        ++o;
        m &= m - 1;
      }
    }
    #pragma unroll
    for (int rr = 0; rr < 8; ++rr) av[rr] = nv[rr];
  }

  // ---- merge col masks across waves via LDS, one atomic per column ----
  #pragma unroll
  for (int k = 0; k < 4; ++k) {
    colLDS[lane * 4 + k][wave * 2 + 0] = cacc[k * 2 + 0];
    colLDS[lane * 4 + k][wave * 2 + 1] = cacc[k * 2 + 1];
  }
  __syncthreads();
  {
    const int j = threadIdx.x;         // col 0..255
    unsigned int m8[8];
    int tot = 0;
    #pragma unroll
    for (int w = 0; w < 8; ++w) { m8[w] = colLDS[j][w]; tot += __popc(m8[w]); }
    if (tot > 0) {
      const int R = (NC + c) * 6144 + tv * 256 + j;
      int o = atomicAdd(&cnt[R], tot);
      unsigned short* orow = idx + (size_t)R * CAP;
      #pragma unroll
      for (int w = 0; w < 8; ++w) {
        unsigned int m = m8[w];
        const int ub = tu * 256 + (w >> 1) * 64 + (w & 1) * 32;
        while (m) {
          const int bb = __ffs(m) - 1;
          if (o < CAP) orow[o] = (unsigned short)(ub + bb);
          ++o;
          m &= m - 1;
        }
      }
    }
  }
}

// ---------------------------------------------------------------------------
// Fused layer: gather (5 classes x 16 rows -> LDS) + 5-class 64x64 GEMM.
//   blocks 0..383  : side A rows r0=blk*16       (gathers tabA, W=Wa, out=outA)
//   blocks 384..767: side B rows r0=(blk-384)*16 (gathers tabB, W=Wb, out=outB)
// ---------------------------------------------------------------------------
__global__ __launch_bounds__(256) void k_layer(
    const int* __restrict__ cnt,             // [2*HALF]
    const unsigned short* __restrict__ idx,  // [2*HALF][CAP]
    const float* __restrict__ tabA,          // [6144][64]
    const float* __restrict__ tabB,          // [6144][64]
    const float* __restrict__ Wa, const float* __restrict__ ba,
    float* __restrict__ outA,
    const float* __restrict__ Wb, const float* __restrict__ bb,
    float* __restrict__ outB,
    int do_relu) {
  __shared__ float4 lds_agg[NC][16][16];     // 20 KB
  const int side = blockIdx.x >= 384;
  const int r0   = (blockIdx.x - side * 384) * 16;
  const float4* tab = (const float4*)(side ? tabB : tabA);
  const float* W    = side ? Wb : Wa;
  const float* bias = side ? bb : ba;
  float* out        = side ? outB : outA;
  const int wave = threadIdx.x >> 6;
  const int lane = threadIdx.x & 63;
  const int g    = lane >> 4;
  const int e16  = lane & 15;

  // ---- gather phase: 20 (c,row) tasks for this wave ----
  for (int rr = wave * 4; rr < wave * 4 + 4; ++rr) {
    for (int c = 0; c < NC; ++c) {
      const int R = side * HALF + c * 6144 + r0 + rr;
      int n = cnt[R];
      n = n > CAP ? CAP : n;
      const unsigned short* l = idx + (size_t)R * CAP;
      float4 a0 = make_float4(0.f,0.f,0.f,0.f), a1 = a0, a2 = a0, a3 = a0;
      int i = 0;
      for (; i + 16 <= n; i += 16) {
        const int j0 = l[i + g], j1 = l[i + 4 + g];
        const int j2 = l[i + 8 + g], j3 = l[i + 12 + g];
        const float4 x0 = tab[j0 * 16 + e16];
        const float4 x1 = tab[j1 * 16 + e16];
        const float4 x2 = tab[j2 * 16 + e16];
        const float4 x3 = tab[j3 * 16 + e16];
        a0.x += x0.x; a0.y += x0.y; a0.z += x0.z; a0.w += x0.w;
        a1.x += x1.x; a1.y += x1.y; a1.z += x1.z; a1.w += x1.w;
        a2.x += x2.x; a2.y += x2.y; a2.z += x2.z; a2.w += x2.w;
        a3.x += x3.x; a3.y += x3.y; a3.z += x3.z; a3.w += x3.w;
      }
      for (; i + 4 <= n; i += 4) {
        const float4 x = tab[(int)l[i + g] * 16 + e16];
        a0.x += x.x; a0.y += x.y; a0.z += x.z; a0.w += x.w;
      }
      if (i + g < n) {
        const float4 x = tab[(int)l[i + g] * 16 + e16];
        a1.x += x.x; a1.y += x.y; a1.z += x.z; a1.w += x.w;
      }
      a0.x += a1.x + a2.x + a3.x;
      a0.y += a1.y + a2.y + a3.y;
      a0.z += a1.z + a2.z + a3.z;
      a0.w += a1.w + a2.w + a3.w;
      #pragma unroll
      for (int off = 16; off < 64; off <<= 1) {
        a0.x += __shfl_xor(a0.x, off, 64);
        a0.y += __shfl_xor(a0.y, off, 64);
        a0.z += __shfl_xor(a0.z, off, 64);
        a0.w += __shfl_xor(a0.w, off, 64);
      }
      if (g == 0) lds_agg[c][rr][e16] = a0;
    }
  }
  __syncthreads();

  // ---- GEMM phase: wave computes rows r0+wave*4 .. +3 ----
  float bs = 0.0f;
  #pragma unroll
  for (int c = 0; c < NC; ++c) bs += bias[c * 64 + lane];
  float acc[4] = {bs, bs, bs, bs};
  for (int c = 0; c < NC; ++c) {
    float w[64];
    #pragma unroll
    for (int d = 0; d < 64; ++d) w[d] = W[c * 4096 + d * 64 + lane];
    #pragma unroll
    for (int r = 0; r < 4; ++r) {
      #pragma unroll
      for (int d4 = 0; d4 < 16; ++d4) {
        const float4 a = lds_agg[c][wave * 4 + r][d4];   // LDS broadcast
        acc[r] = fmaf(a.x, w[d4 * 4 + 0], acc[r]);
        acc[r] = fmaf(a.y, w[d4 * 4 + 1], acc[r]);
        acc[r] = fmaf(a.z, w[d4 * 4 + 2], acc[r]);
        acc[r] = fmaf(a.w, w[d4 * 4 + 3], acc[r]);
      }
    }
  }
  #pragma unroll
  for (int r = 0; r < 4; ++r) {
    const float v = do_relu ? fmaxf(acc[r], 0.0f) : acc[r];
    out[(size_t)(r0 + wave * 4 + r) * 64 + lane] = v;
  }
}

// ---------------------------------------------------------------------------
// Decoder: logits[b,c] = sum_{d,e} z_u[u[b],d] * Q[c,d,e] * z_v[v[b],e]
// ---------------------------------------------------------------------------
__global__ __launch_bounds__(256) void k_decoder(
    const int* __restrict__ uu, const int* __restrict__ vv,
    const float* __restrict__ z_u, const float* __restrict__ z_v,
    const float* __restrict__ Q,   // C x 64 x 64
    float* __restrict__ out) {     // B x C
  const int lane = threadIdx.x & 63;
  const int wave = threadIdx.x >> 6;
  const int b = blockIdx.x * 4 + wave;
  const int ub = uu[b];
  const int vb = vv[b];
  const float zve = z_v[(size_t)vb * 64 + lane];
  const float* zu = z_u + (size_t)ub * 64;            // wave-uniform reads
  #pragma unroll
  for (int c = 0; c < NC; ++c) {
    const float* Qc = Q + c * 64 * 64;
    float t = 0.0f;
    #pragma unroll
    for (int d = 0; d < 64; ++d) t = fmaf(zu[d], Qc[d * 64 + lane], t);
    float p = t * zve;
    #pragma unroll
    for (int off = 32; off > 0; off >>= 1) p += __shfl_xor(p, off, 64);
    if (lane == 0) out[(size_t)b * NC + c] = p;
  }
}

extern "C" void kernel_launch(void* const* d_in, const int* in_sizes, int n_in,
                              void* d_out, int out_size, void* d_ws, size_t ws_size,
                              hipStream_t stream) {
  const int*   u     = (const int*)d_in[0];
  const int*   v     = (const int*)d_in[1];
  const float* u_emb = (const float*)d_in[2];
  const float* v_emb = (const float*)d_in[3];
  const float* W1u   = (const float*)d_in[4];
  const float* b1u   = (const float*)d_in[5];
  const float* W1v   = (const float*)d_in[6];
  const float* b1v   = (const float*)d_in[7];
  const float* W2u   = (const float*)d_in[8];
  const float* b2u   = (const float*)d_in[9];
  const float* W2v   = (const float*)d_in[10];
  const float* b2v   = (const float*)d_in[11];
  const float* Q     = (const float*)d_in[12];
  const float* adj   = (const float*)d_in[13];
  float* out = (float*)d_out;

  // ---- workspace carve-up (~22 MB) ----
  char* ws = (char*)d_ws;
  int* cnt = (int*)ws;                                       //   245,760 B
  unsigned short* idxL = (unsigned short*)(ws + 245760);     // 15,728,640 B
  char* fbase = ws + 245760 + 15728640;
  float* h_u = (float*)fbase;
  float* h_v = (float*)(fbase + 1572864);
  float* z_u = (float*)(fbase + 3145728);
  float* z_v = (float*)(fbase + 4718592);                    // ends ~22 MB

  // zero the counters (ws is poisoned 0xAA each call)
  (void)hipMemsetAsync(cnt, 0, 2 * NC * 6144 * sizeof(int), stream);

  // One pass over adj -> CSR + CSC index lists (256x256 tiles, pipelined)
  k_adj2idx<<<NC * 24 * 24, 256, 0, stream>>>(adj, cnt, idxL);

  // layer 1: fused gather+GEMM (both sides in one launch)
  k_layer<<<768, 256, 0, stream>>>(cnt, idxL, v_emb, u_emb,
                                   W1v, b1v, h_u, W1u, b1u, h_v, 1);
  // layer 2
  k_layer<<<768, 256, 0, stream>>>(cnt, idxL, h_v, h_u,
                                   W2u, b2u, z_u, W2v, b2v, z_v, 0);
  // bilinear decoder
  k_decoder<<<NB / 4, 256, 0, stream>>>(u, v, z_u, z_v, Q, out);
}

// Round 9
// 1174.051 us; speedup vs baseline: 1.0095x; 1.0095x over previous
//
#include <hip/hip_runtime.h>

// Problem constants
#define NC   5
#define NU   6144
#define NV   6144
#define ND   64
#define NB   4096
#define CAP  128     // max nnz per row/col per class (mean 61.4, +8.5 sigma)
#define HALF (NC * NU)   // 30720 rows per side

// spread bits of a byte to every 4th bit of a u32
__device__ __forceinline__ unsigned int spread4(unsigned int x) {
  x &= 0xFFu;
  x = (x | (x << 12)) & 0x000F000Fu;
  x = (x | (x << 6))  & 0x03030303u;
  x = (x | (x << 3))  & 0x11111111u;
  return x;
}

// ---------------------------------------------------------------------------
// One pass: dense adj [C,U,V] fp32 (exactly 0/1) -> CSR + CSC index lists.
// Tile = 64 u x 256 v per block, XCD-swizzled so all 24 tv-tiles of one
// (c,tu) row-stripe run on the same XCD (row-side cnt/idx stays XCD-local).
// Best-measured variant (R6: 1164.6 us total).
// ---------------------------------------------------------------------------
__global__ __launch_bounds__(256) void k_adj2idx(
    const float* __restrict__ adj,
    int* __restrict__ cnt,                // [2*C*6144] (csr | csc)
    unsigned short* __restrict__ idx) {   // [2*C*6144][CAP]
  __shared__ unsigned int rowwords[64][9];   // +1 pad
  // ---- swizzled tile decode: stripe S=(c*96+tu) pinned to XCD S%8 ----
  const int x = blockIdx.x & 7;
  const int s = blockIdx.x >> 3;             // 0..1439
  const int tv = s % 24;
  const int S = (s / 24) * 8 + x;            // 0..479
  const int c  = S / 96;
  const int tu = S - c * 96;
  const int wave = threadIdx.x >> 6;
  const int lane = threadIdx.x & 63;

  // ---- load + ballot-pack 16 rows per wave ----
  float4 av[16];
  {
    const float* base = adj +
        ((size_t)(c * NU + tu * 64 + wave * 16) * NV + tv * 256);
    #pragma unroll
    for (int rr = 0; rr < 16; ++rr)
      av[rr] = ((const float4*)(base + (size_t)rr * NV))[lane];
  }
  #pragma unroll
  for (int rr = 0; rr < 16; ++rr) {
    const unsigned long long b0 = __ballot(av[rr].x != 0.0f);
    const unsigned long long b1 = __ballot(av[rr].y != 0.0f);
    const unsigned long long b2 = __ballot(av[rr].z != 0.0f);
    const unsigned long long b3 = __ballot(av[rr].w != 0.0f);
    if (lane < 8) {                    // word w = lane covers lanes w*8..w*8+7
      const unsigned int e0 = spread4((unsigned int)(b0 >> (lane * 8)));
      const unsigned int e1 = spread4((unsigned int)(b1 >> (lane * 8)));
      const unsigned int e2 = spread4((unsigned int)(b2 >> (lane * 8)));
      const unsigned int e3 = spread4((unsigned int)(b3 >> (lane * 8)));
      rowwords[wave * 16 + rr][lane] = e0 | (e1 << 1) | (e2 << 2) | (e3 << 3);
    }
  }
  __syncthreads();

  // ---- row side: 2 passes of 8 rows x 8 words per wave ----
  #pragma unroll
  for (int p = 0; p < 2; ++p) {
    const int rloc = lane >> 3;        // row within pass (0..7)
    const int wloc = lane & 7;         // word (0..7)
    const int r = wave * 16 + p * 8 + rloc;          // tile row 0..63
    const unsigned int wbits = rowwords[r][wloc];
    const int pc = __popc(wbits);
    int pre = pc;                      // inclusive prefix within 8-lane group
    #pragma unroll
    for (int d = 1; d < 8; d <<= 1) {
      const int y = __shfl_up(pre, d, 64);
      if (wloc >= d) pre += y;
    }
    const int total = __shfl(pre, rloc * 8 + 7, 64);
    const int excl  = pre - pc;
    const int R = c * 6144 + tu * 64 + r;            // csr row id
    int base = 0;
    if (wloc == 0 && total > 0) base = atomicAdd(&cnt[R], total);
    base = __shfl(base, rloc * 8, 64);
    unsigned int m = wbits;
    int o = base + excl;
    unsigned short* orow = idx + (size_t)R * CAP;
    const int vbase = tv * 256 + wloc * 32;
    while (m) {
      const int bb = __ffs(m) - 1;
      if (o < CAP) orow[o] = (unsigned short)(vbase + bb);
      ++o;
      m &= m - 1;
    }
  }

  // ---- col side: bit-transpose in registers, one atomic per nonempty col --
  {
    const int j = threadIdx.x;         // local col 0..255
    const int w = j >> 5, bit = j & 31;
    unsigned int w0 = 0, w1 = 0;
    #pragma unroll
    for (int r = 0; r < 32; ++r) {
      w0 |= ((rowwords[r][w]      >> bit) & 1u) << r;   // broadcast reads
      w1 |= ((rowwords[r + 32][w] >> bit) & 1u) << r;
    }
    const int cj = __popc(w0) + __popc(w1);
    if (cj > 0) {
      const int R = (NC + c) * 6144 + tv * 256 + j;    // csc row id
      int o = atomicAdd(&cnt[R], cj);
      unsigned short* orow = idx + (size_t)R * CAP;
      const int ubase = tu * 64;
      unsigned int m = w0;
      while (m) {
        const int bb = __ffs(m) - 1;
        if (o < CAP) orow[o] = (unsigned short)(ubase + bb);
        ++o;
        m &= m - 1;
      }
      m = w1;
      while (m) {
        const int bb = __ffs(m) - 1;
        if (o < CAP) orow[o] = (unsigned short)(ubase + 32 + bb);
        ++o;
        m &= m - 1;
      }
    }
  }
}

// ---------------------------------------------------------------------------
// Fused layer: gather (5 classes x 16 rows -> LDS) + 5-class 64x64 GEMM.
//   blocks 0..383  : side A rows r0=blk*16       (gathers tabA, W=Wa, out=outA)
//   blocks 384..767: side B rows r0=(blk-384)*16 (gathers tabB, W=Wb, out=outB)
// ---------------------------------------------------------------------------
__global__ __launch_bounds__(256) void k_layer(
    const int* __restrict__ cnt,             // [2*HALF]
    const unsigned short* __restrict__ idx,  // [2*HALF][CAP]
    const float* __restrict__ tabA,          // [6144][64]
    const float* __restrict__ tabB,          // [6144][64]
    const float* __restrict__ Wa, const float* __restrict__ ba,
    float* __restrict__ outA,
    const float* __restrict__ Wb, const float* __restrict__ bb,
    float* __restrict__ outB,
    int do_relu) {
  __shared__ float4 lds_agg[NC][16][16];     // 20 KB
  const int side = blockIdx.x >= 384;
  const int r0   = (blockIdx.x - side * 384) * 16;
  const float4* tab = (const float4*)(side ? tabB : tabA);
  const float* W    = side ? Wb : Wa;
  const float* bias = side ? bb : ba;
  float* out        = side ? outB : outA;
  const int wave = threadIdx.x >> 6;
  const int lane = threadIdx.x & 63;
  const int g    = lane >> 4;
  const int e16  = lane & 15;

  // ---- gather phase: 20 (c,row) tasks for this wave ----
  for (int rr = wave * 4; rr < wave * 4 + 4; ++rr) {
    for (int c = 0; c < NC; ++c) {
      const int R = side * HALF + c * 6144 + r0 + rr;
      int n = cnt[R];
      n = n > CAP ? CAP : n;
      const unsigned short* l = idx + (size_t)R * CAP;
      float4 a0 = make_float4(0.f,0.f,0.f,0.f), a1 = a0, a2 = a0, a3 = a0;
      int i = 0;
      for (; i + 16 <= n; i += 16) {
        const int j0 = l[i + g], j1 = l[i + 4 + g];
        const int j2 = l[i + 8 + g], j3 = l[i + 12 + g];
        const float4 x0 = tab[j0 * 16 + e16];
        const float4 x1 = tab[j1 * 16 + e16];
        const float4 x2 = tab[j2 * 16 + e16];
        const float4 x3 = tab[j3 * 16 + e16];
        a0.x += x0.x; a0.y += x0.y; a0.z += x0.z; a0.w += x0.w;
        a1.x += x1.x; a1.y += x1.y; a1.z += x1.z; a1.w += x1.w;
        a2.x += x2.x; a2.y += x2.y; a2.z += x2.z; a2.w += x2.w;
        a3.x += x3.x; a3.y += x3.y; a3.z += x3.z; a3.w += x3.w;
      }
      for (; i + 4 <= n; i += 4) {
        const float4 x = tab[(int)l[i + g] * 16 + e16];
        a0.x += x.x; a0.y += x.y; a0.z += x.z; a0.w += x.w;
      }
      if (i + g < n) {
        const float4 x = tab[(int)l[i + g] * 16 + e16];
        a1.x += x.x; a1.y += x.y; a1.z += x.z; a1.w += x.w;
      }
      a0.x += a1.x + a2.x + a3.x;
      a0.y += a1.y + a2.y + a3.y;
      a0.z += a1.z + a2.z + a3.z;
      a0.w += a1.w + a2.w + a3.w;
      #pragma unroll
      for (int off = 16; off < 64; off <<= 1) {
        a0.x += __shfl_xor(a0.x, off, 64);
        a0.y += __shfl_xor(a0.y, off, 64);
        a0.z += __shfl_xor(a0.z, off, 64);
        a0.w += __shfl_xor(a0.w, off, 64);
      }
      if (g == 0) lds_agg[c][rr][e16] = a0;
    }
  }
  __syncthreads();

  // ---- GEMM phase: wave computes rows r0+wave*4 .. +3 ----
  float bs = 0.0f;
  #pragma unroll
  for (int c = 0; c < NC; ++c) bs += bias[c * 64 + lane];
  float acc[4] = {bs, bs, bs, bs};
  for (int c = 0; c < NC; ++c) {
    float w[64];
    #pragma unroll
    for (int d = 0; d < 64; ++d) w[d] = W[c * 4096 + d * 64 + lane];
    #pragma unroll
    for (int r = 0; r < 4; ++r) {
      #pragma unroll
      for (int d4 = 0; d4 < 16; ++d4) {
        const float4 a = lds_agg[c][wave * 4 + r][d4];   // LDS broadcast
        acc[r] = fmaf(a.x, w[d4 * 4 + 0], acc[r]);
        acc[r] = fmaf(a.y, w[d4 * 4 + 1], acc[r]);
        acc[r] = fmaf(a.z, w[d4 * 4 + 2], acc[r]);
        acc[r] = fmaf(a.w, w[d4 * 4 + 3], acc[r]);
      }
    }
  }
  #pragma unroll
  for (int r = 0; r < 4; ++r) {
    const float v = do_relu ? fmaxf(acc[r], 0.0f) : acc[r];
    out[(size_t)(r0 + wave * 4 + r) * 64 + lane] = v;
  }
}

// ---------------------------------------------------------------------------
// Decoder: logits[b,c] = sum_{d,e} z_u[u[b],d] * Q[c,d,e] * z_v[v[b],e]
// ---------------------------------------------------------------------------
__global__ __launch_bounds__(256) void k_decoder(
    const int* __restrict__ uu, const int* __restrict__ vv,
    const float* __restrict__ z_u, const float* __restrict__ z_v,
    const float* __restrict__ Q,   // C x 64 x 64
    float* __restrict__ out) {     // B x C
  const int lane = threadIdx.x & 63;
  const int wave = threadIdx.x >> 6;
  const int b = blockIdx.x * 4 + wave;
  const int ub = uu[b];
  const int vb = vv[b];
  const float zve = z_v[(size_t)vb * 64 + lane];
  const float* zu = z_u + (size_t)ub * 64;            // wave-uniform reads
  #pragma unroll
  for (int c = 0; c < NC; ++c) {
    const float* Qc = Q + c * 64 * 64;
    float t = 0.0f;
    #pragma unroll
    for (int d = 0; d < 64; ++d) t = fmaf(zu[d], Qc[d * 64 + lane], t);
    float p = t * zve;
    #pragma unroll
    for (int off = 32; off > 0; off >>= 1) p += __shfl_xor(p, off, 64);
    if (lane == 0) out[(size_t)b * NC + c] = p;
  }
}

extern "C" void kernel_launch(void* const* d_in, const int* in_sizes, int n_in,
                              void* d_out, int out_size, void* d_ws, size_t ws_size,
                              hipStream_t stream) {
  const int*   u     = (const int*)d_in[0];
  const int*   v     = (const int*)d_in[1];
  const float* u_emb = (const float*)d_in[2];
  const float* v_emb = (const float*)d_in[3];
  const float* W1u   = (const float*)d_in[4];
  const float* b1u   = (const float*)d_in[5];
  const float* W1v   = (const float*)d_in[6];
  const float* b1v   = (const float*)d_in[7];
  const float* W2u   = (const float*)d_in[8];
  const float* b2u   = (const float*)d_in[9];
  const float* W2v   = (const float*)d_in[10];
  const float* b2v   = (const float*)d_in[11];
  const float* Q     = (const float*)d_in[12];
  const float* adj   = (const float*)d_in[13];
  float* out = (float*)d_out;

  // ---- workspace carve-up (~22 MB) ----
  char* ws = (char*)d_ws;
  int* cnt = (int*)ws;                                       //   245,760 B
  unsigned short* idxL = (unsigned short*)(ws + 245760);     // 15,728,640 B
  char* fbase = ws + 245760 + 15728640;
  float* h_u = (float*)fbase;
  float* h_v = (float*)(fbase + 1572864);
  float* z_u = (float*)(fbase + 3145728);
  float* z_v = (float*)(fbase + 4718592);                    // ends ~22 MB

  // zero the counters (ws is poisoned 0xAA each call)
  (void)hipMemsetAsync(cnt, 0, 2 * NC * 6144 * sizeof(int), stream);

  // One pass over adj -> CSR + CSC index lists (XCD-swizzled tiles)
  k_adj2idx<<<NC * 96 * 24, 256, 0, stream>>>(adj, cnt, idxL);

  // layer 1: fused gather+GEMM (both sides in one launch)
  k_layer<<<768, 256, 0, stream>>>(cnt, idxL, v_emb, u_emb,
                                   W1v, b1v, h_u, W1u, b1u, h_v, 1);
  // layer 2
  k_layer<<<768, 256, 0, stream>>>(cnt, idxL, h_v, h_u,
                                   W2u, b2u, z_u, W2v, b2v, z_v, 0);
  // bilinear decoder
  k_decoder<<<NB / 4, 256, 0, stream>>>(u, v, z_u, z_v, Q, out);
}